// Round 6
// baseline (394.313 us; speedup 1.0000x reference)
//
#include <hip/hip_runtime.h>
#include <hip/hip_bf16.h>

// RefinementLayer2: B=2,S=384,C=4,H=128,D=768 — single kernel, SW grid barrier.
// ws layout (floats):
//   0        tanh_h   (786432) = tanh(seq@{Wp,Ua}+b), z=0/1 slices (768,512)
//   786432   h_a      (393216) = seq@Ua+b         (768,512)
//   1179648  tprd_s   (393216) = C2*tanh(h_p)@W1  (3072,128)
//   1572864  tref_s   (98304)  = C2*tanh(ref)@W3  (768,128)  [atomic-accum]
//   1671168  targ_s   (196608 floats as bf16)     (3072,128)
// barrier cells at byte offset 16 MiB into d_ws.

#define C2 2.885390081777927f  // 2/ln(2): exp2(C2*x) = e^(2x)
#define NBLK 512
#define MAGIC 0x13579BDFu

typedef __attribute__((ext_vector_type(8))) __bf16 bf16x8;
typedef __attribute__((ext_vector_type(8))) unsigned short ushort8;
typedef __attribute__((ext_vector_type(4))) float float4v;

__device__ __forceinline__ unsigned short f2bf(float f) {
  unsigned int u = __float_as_uint(f);
  u += 0x7fffu + ((u >> 16) & 1u);
  return (unsigned short)(u >> 16);
}

__device__ __forceinline__ float fast_tanh(float x) {
  float e = __builtin_amdgcn_exp2f(C2 * x);
  return 1.0f - 2.0f * __builtin_amdgcn_rcpf(1.0f + e);
}

// 64x64-tile bf16-MFMA core, BK=32, 256 threads (4 waves, 32x32 each).
__device__ __forceinline__ void gemm_core(
    const float* __restrict__ Abase, int lda,
    const float* __restrict__ Bbase, int ldb, int K,
    unsigned short* Alds, unsigned short* Blds,
    int ar, int ac, int bk, int bn,
    int wm0, int wn0, int col16, int quad, float4v acc[2][2])
{
  const float* Ap = Abase + (size_t)ar * lda + ac;
  const float* Bp = Bbase + (size_t)bk * ldb + bn;
  float4 a0 = ((const float4*)Ap)[0], a1 = ((const float4*)Ap)[1];
  float4 b0 = ((const float4*)Bp)[0], b1 = ((const float4*)Bp)[1];

  for (int k0 = 0; k0 < K; k0 += 32) {
    __syncthreads();
    {
      ushort8 o;
      o[0] = f2bf(a0.x); o[1] = f2bf(a0.y); o[2] = f2bf(a0.z); o[3] = f2bf(a0.w);
      o[4] = f2bf(a1.x); o[5] = f2bf(a1.y); o[6] = f2bf(a1.z); o[7] = f2bf(a1.w);
      *(ushort8*)&Alds[ar * 40 + ac] = o;
      float vv[8] = {b0.x, b0.y, b0.z, b0.w, b1.x, b1.y, b1.z, b1.w};
#pragma unroll
      for (int j = 0; j < 8; ++j) Blds[(bn + j) * 40 + bk] = f2bf(vv[j]);
    }
    __syncthreads();
    if (k0 + 32 < K) {
      const float4* An = (const float4*)(Ap + k0 + 32);
      const float4* Bn = (const float4*)(Bp + (size_t)(k0 + 32) * ldb);
      a0 = An[0]; a1 = An[1]; b0 = Bn[0]; b1 = Bn[1];
    }
    bf16x8 afrag[2], bfrag[2];
#pragma unroll
    for (int i = 0; i < 2; ++i)
      afrag[i] = __builtin_bit_cast(bf16x8,
          *(const ushort8*)&Alds[(wm0 + i * 16 + col16) * 40 + quad * 8]);
#pragma unroll
    for (int j = 0; j < 2; ++j)
      bfrag[j] = __builtin_bit_cast(bf16x8,
          *(const ushort8*)&Blds[(wn0 + j * 16 + col16) * 40 + quad * 8]);
#pragma unroll
    for (int i = 0; i < 2; ++i)
#pragma unroll
      for (int j = 0; j < 2; ++j)
        acc[i][j] = __builtin_amdgcn_mfma_f32_16x16x32_bf16(
            afrag[i], bfrag[j], acc[i][j], 0, 0, 0);
  }
}

// Software grid barrier. cnt: 8 spread counters (stride 32 u32 = 128 B).
// Block 0 polls the counters and releases; others spin on rel.
// Bounded spins: on a bug we produce wrong results instead of hanging.
__device__ __forceinline__ void grid_barrier(unsigned* cnt, unsigned* rel,
                                             int bid) {
  __syncthreads();
  if (threadIdx.x == 0) {
    __hip_atomic_fetch_add(&cnt[(bid & 7) * 32], 1u, __ATOMIC_ACQ_REL,
                           __HIP_MEMORY_SCOPE_AGENT);
    if (bid == 0) {
      for (long g = 0; g < (1L << 24); ++g) {
        unsigned s = 0;
#pragma unroll
        for (int i = 0; i < 8; ++i)
          s += __hip_atomic_load(&cnt[i * 32], __ATOMIC_ACQUIRE,
                                 __HIP_MEMORY_SCOPE_AGENT);
        if (s == NBLK) break;
        __builtin_amdgcn_s_sleep(2);
      }
      __hip_atomic_store(rel, MAGIC, __ATOMIC_RELEASE,
                         __HIP_MEMORY_SCOPE_AGENT);
    } else {
      for (long g = 0; g < (1L << 24); ++g) {
        if (__hip_atomic_load(rel, __ATOMIC_ACQUIRE,
                              __HIP_MEMORY_SCOPE_AGENT) == MAGIC) break;
        __builtin_amdgcn_s_sleep(2);
      }
    }
  }
  __syncthreads();
}

// __launch_bounds__(256,2): cap = 256 VGPR/wave (no spills — R5's (256,4)
// capped at ~64-128 incl AGPRs and spilled to scratch: 337us, VALUBusy 5%).
// Co-residency: LDS 28.7KB -> 5 blocks/CU, bound guarantees >=2; grid 512
// <= 2*256, so the barrier cannot deadlock.
__global__ __launch_bounds__(256, 2) void mono(
    const float* __restrict__ seq, const float* __restrict__ base,
    const float* __restrict__ Wp, const float* __restrict__ Wpb,
    const float* __restrict__ Ua, const float* __restrict__ Uab,
    const float* __restrict__ Wmid, const float* __restrict__ bmid,
    const float* __restrict__ wout, float* __restrict__ out,
    float* __restrict__ tanh_h, float* __restrict__ h_a,
    float* __restrict__ tprd_s, float* __restrict__ tref_s,
    unsigned short* __restrict__ targ_s, unsigned* __restrict__ bar)
{
  __shared__ __align__(16) unsigned char smem[28672];
  unsigned short* Alds = (unsigned short*)smem;            // 5120 B
  unsigned short* Blds = (unsigned short*)(smem + 5120);   // 5120 B

  const int tid = threadIdx.x;
  const int bid = blockIdx.x;
  const int wid = tid >> 6, lane = tid & 63;
  const int wm0 = (wid >> 1) * 32, wn0 = (wid & 1) * 32;
  const int col16 = lane & 15, quad = lane >> 4;
  const int ar = tid >> 2, ac = (tid & 3) * 8;
  const int bk = tid >> 3, bn = (tid & 7) * 8;

  // ---- barrier init (block 0) + ready handshake ----
  if (bid == 0 && tid == 0) {
#pragma unroll
    for (int i = 0; i < 8; ++i) {
      __hip_atomic_store(&bar[32 + i * 32], 0u, __ATOMIC_RELAXED,
                         __HIP_MEMORY_SCOPE_AGENT);
      __hip_atomic_store(&bar[512 + i * 32], 0u, __ATOMIC_RELAXED,
                         __HIP_MEMORY_SCOPE_AGENT);
    }
    __hip_atomic_store(&bar[16], 0u, __ATOMIC_RELAXED, __HIP_MEMORY_SCOPE_AGENT);
    __hip_atomic_store(&bar[24], 0u, __ATOMIC_RELAXED, __HIP_MEMORY_SCOPE_AGENT);
    __hip_atomic_store(&bar[0], MAGIC, __ATOMIC_RELEASE,
                       __HIP_MEMORY_SCOPE_AGENT);
  }

  // ---------------- Stage 1 ----------------
  if (bid < 192) {
    const int z = bid / 96, rem = bid % 96;
    const int bn0 = (rem & 7) * 64, bm0 = (rem >> 3) * 64;
    const float* Bm = (z ? Ua : Wp) + bn0;
    const float* bias = z ? Uab : Wpb;
    float4v acc[2][2];
#pragma unroll
    for (int i = 0; i < 2; ++i)
#pragma unroll
      for (int j = 0; j < 2; ++j) acc[i][j] = (float4v)(0.f);
    gemm_core(seq + (size_t)bm0 * 768, 768, Bm, 512, 768,
              Alds, Blds, ar, ac, bk, bn, wm0, wn0, col16, quad, acc);
    float* tout = tanh_h + (size_t)z * 393216;
#pragma unroll
    for (int j = 0; j < 2; ++j) {
      const int gcol = bn0 + wn0 + j * 16 + col16;
      const float bv = bias[gcol];
#pragma unroll
      for (int i = 0; i < 2; ++i)
#pragma unroll
        for (int r = 0; r < 4; ++r) {
          const int grow = bm0 + wm0 + i * 16 + quad * 4 + r;
          const float x = acc[i][j][r] + bv;
          const size_t cidx = (size_t)grow * 512 + gcol;
          tout[cidx] = fast_tanh(x);
          if (z == 1) h_a[cidx] = x;
        }
    }
  } else {
    for (int idx = (bid - 192) * 256 + tid; idx < 98304; idx += 81920)
      tref_s[idx] = 0.f;
  }

  // ready handshake then barrier 1
  if (tid == 0) {
    for (long g = 0; g < (1L << 24); ++g) {
      if (__hip_atomic_load(&bar[0], __ATOMIC_ACQUIRE,
                            __HIP_MEMORY_SCOPE_AGENT) == MAGIC) break;
      __builtin_amdgcn_s_sleep(2);
    }
  }
  grid_barrier(&bar[32], &bar[16], bid);

  // ---------------- Stage 2 ----------------
  if (bid < 288) {
    float4v acc[2][2];
#pragma unroll
    for (int i = 0; i < 2; ++i)
#pragma unroll
      for (int j = 0; j < 2; ++j) acc[i][j] = (float4v)(0.f);

    if (bid < 96) {  // heavy: ref tile + tanh + tail MFMA -> atomic tref
      unsigned short* TA = (unsigned short*)smem;           // 64x72, 9216 B
      unsigned short* TB = (unsigned short*)(smem + 9216);  // 128x72, 18432 B
      const int z = bid / 12, rem = bid % 12;
      const int b = z >> 2, c = z & 3;
      const int y = rem >> 1, x = rem & 1;
      const float* A = base + (size_t)b * 589824 + c * 384 + (size_t)(y * 64) * 1536;
      const float* Bm = h_a + (size_t)b * 196608 + c * 128 + x * 64;
      gemm_core(A, 1536, Bm, 512, 384, Alds, Blds, ar, ac, bk, bn,
                wm0, wn0, col16, quad, acc);
      __syncthreads();  // TA overlaps Alds/Blds — drain gemm_core LDS reads
#pragma unroll
      for (int j = 0; j < 2; ++j)
#pragma unroll
        for (int i = 0; i < 2; ++i)
#pragma unroll
          for (int r = 0; r < 4; ++r)
            TA[(wm0 + i * 16 + quad * 4 + r) * 72 + wn0 + j * 16 + col16] =
                f2bf(fast_tanh(acc[i][j][r]));
      {
        const float* W3p = Wmid + 32768 + (size_t)(c * 128 + x * 64) * 128;
        const int kr = tid >> 2, nb = (tid & 3) * 32;
#pragma unroll
        for (int q = 0; q < 8; ++q) {
          float4 v = *(const float4*)(W3p + (size_t)kr * 128 + nb + q * 4);
          TB[(nb + q * 4 + 0) * 72 + kr] = f2bf(v.x);
          TB[(nb + q * 4 + 1) * 72 + kr] = f2bf(v.y);
          TB[(nb + q * 4 + 2) * 72 + kr] = f2bf(v.z);
          TB[(nb + q * 4 + 3) * 72 + kr] = f2bf(v.w);
        }
      }
      __syncthreads();
      const int mh = wid & 1, nh = wid >> 1;
      float4v acc2[2][4];
#pragma unroll
      for (int i = 0; i < 2; ++i)
#pragma unroll
        for (int j = 0; j < 4; ++j) acc2[i][j] = (float4v)(0.f);
#pragma unroll
      for (int ks = 0; ks < 2; ++ks) {
        bf16x8 af[2], bf[4];
#pragma unroll
        for (int i = 0; i < 2; ++i)
          af[i] = __builtin_bit_cast(bf16x8,
              *(const ushort8*)&TA[(mh * 32 + i * 16 + col16) * 72 + ks * 32 + quad * 8]);
#pragma unroll
        for (int j = 0; j < 4; ++j)
          bf[j] = __builtin_bit_cast(bf16x8,
              *(const ushort8*)&TB[(nh * 64 + j * 16 + col16) * 72 + ks * 32 + quad * 8]);
#pragma unroll
        for (int i = 0; i < 2; ++i)
#pragma unroll
          for (int j = 0; j < 4; ++j)
            acc2[i][j] = __builtin_amdgcn_mfma_f32_16x16x32_bf16(
                af[i], bf[j], acc2[i][j], 0, 0, 0);
      }
#pragma unroll
      for (int j = 0; j < 4; ++j) {
        const int gcol = nh * 64 + j * 16 + col16;
#pragma unroll
        for (int i = 0; i < 2; ++i)
#pragma unroll
          for (int r = 0; r < 4; ++r) {
            const int grow = b * 384 + y * 64 + mh * 32 + i * 16 + quad * 4 + r;
            atomicAdd(&tref_s[(size_t)grow * 128 + gcol], C2 * acc2[i][j][r]);
          }
      }
    } else {  // light: tanh_h{p,a}@W{1,2}
      const int idx = bid - 96;
      const int x = idx & 1, y = (idx >> 1) % 48, z = idx / 96;
      const float* A = tanh_h + (size_t)z * 393216 + (size_t)(y * 64) * 128;
      const float* Bm = Wmid + z * 16384 + x * 64;
      gemm_core(A, 128, Bm, 128, 128, Alds, Blds, ar, ac, bk, bn,
                wm0, wn0, col16, quad, acc);
#pragma unroll
      for (int j = 0; j < 2; ++j) {
        const int gcol = x * 64 + wn0 + j * 16 + col16;
#pragma unroll
        for (int i = 0; i < 2; ++i)
#pragma unroll
          for (int r = 0; r < 4; ++r) {
            const int grow = y * 64 + wm0 + i * 16 + quad * 4 + r;
            const float v = C2 * acc[i][j][r];
            const size_t cidx = (size_t)grow * 128 + gcol;
            if (z == 0) tprd_s[cidx] = v;
            else        targ_s[cidx] = f2bf(v);
          }
      }
    }
  }

  grid_barrier(&bar[512], &bar[24], bid);

  // ---------------- Stage 3 (phase2) ----------------
  // threads: a = tid&127, kh = tid>>7. k split: h in {0,1} passes of 64 k,
  // each pass kh-split into 32-k quarters. 4-way rcp pairing.
  unsigned int* Gs = (unsigned int*)smem;        // [128][34], 17408 B
  float* Es  = (float*)(smem + 17408);           // [8][128],  4096 B
  float* Ws  = (float*)(smem + 21504);           // [128],      512 B
  float* Red = (float*)(smem + 22016);           // [128][9],  4608 B

  if (tid < 128) Ws[tid] = -2.f * wout[tid];
  float sw = 0.f;
  for (int k4 = 0; k4 < 32; ++k4) {
    float4 w = ((const float4*)wout)[k4];
    sw += w.x + w.y + w.z + w.w;
  }

  const unsigned int* gsrc = (const unsigned int*)targ_s;
  const int a = tid & 127, kh = tid >> 7;
  const int j0 = (bid * 9) >> 2, j1 = ((bid + 1) * 9) >> 2;  // 1152 jobs

  for (int job = j0; job < j1; ++job) {
    const int s = job / 48, pt = job % 48;
    const int at = s % 3, zz = s / 3;
    const int b = zz >> 2, c = zz & 3;
    const int p0 = pt * 8, a0 = at * 128;
    const size_t gb = (size_t)((b * 384 + a0) * 4 + c) * 64;

    __syncthreads();  // prior job's readers done; Ws visible on first
#pragma unroll
    for (int it = 0; it < 4; ++it) {  // Es[8][128]
      int idx = it * 256 + tid;
      int p = idx >> 7, k = idx & 127;
      int row = b * 384 + p0 + p;
      Es[idx] = __builtin_amdgcn_exp2f(
          tprd_s[(size_t)(row * 4 + c) * 128 + k] +
          tref_s[(size_t)row * 128 + k] + C2 * bmid[k]);
    }

    float acc[8];
#pragma unroll
    for (int p = 0; p < 8; ++p) acc[p] = 0.f;

    for (int h = 0; h < 2; ++h) {
      if (h) __syncthreads();  // h=0 compute done reading Gs
#pragma unroll 4
      for (int it = 0; it < 16; ++it) {  // Gs: 128 rows x 32 uints
        int idx = it * 256 + tid;
        int r = idx >> 5, col = idx & 31;
        Gs[r * 34 + col] = gsrc[gb + (size_t)r * 256 + h * 32 + col];
      }
      __syncthreads();

      const unsigned int* g = &Gs[a * 34 + kh * 16];
      const int kb = h * 64 + kh * 32;
#pragma unroll 2
      for (int j = 0; j < 8; ++j) {  // 4 k per j
        uint2 gp = *(const uint2*)(g + j * 2);
        float eg0 = __builtin_amdgcn_exp2f(__uint_as_float(gp.x << 16));
        float eg1 = __builtin_amdgcn_exp2f(__uint_as_float(gp.x & 0xffff0000u));
        float eg2 = __builtin_amdgcn_exp2f(__uint_as_float(gp.y << 16));
        float eg3 = __builtin_amdgcn_exp2f(__uint_as_float(gp.y & 0xffff0000u));
        float4 wq = *(const float4*)&Ws[kb + j * 4];
#pragma unroll
        for (int p = 0; p < 8; ++p) {
          float4 ef = *(const float4*)&Es[p * 128 + kb + j * 4];
          float d0 = fmaf(ef.x, eg0, 1.f);
          float d1 = fmaf(ef.y, eg1, 1.f);
          float d2 = fmaf(ef.z, eg2, 1.f);
          float d3 = fmaf(ef.w, eg3, 1.f);
          float d01 = d0 * d1, d23 = d2 * d3;
          float n01 = fmaf(wq.y, d0, wq.x * d1);
          float n23 = fmaf(wq.w, d2, wq.z * d3);
          float num = fmaf(n01, d23, n23 * d01);
          float r = __builtin_amdgcn_rcpf(d01 * d23);
          acc[p] = fmaf(num, r, acc[p]);
        }
      }
    }

    if (kh) {
#pragma unroll
      for (int p = 0; p < 8; ++p) Red[a * 9 + p] = acc[p];
    }
    __syncthreads();
    if (!kh) {
      const size_t ob = (size_t)((b * 384 + p0) * 4 + c) * 384 + a0 + a;
#pragma unroll
      for (int p = 0; p < 8; ++p)
        out[ob + (size_t)p * 1536] = sw + acc[p] + Red[a * 9 + p];
    }
  }
}

extern "C" void kernel_launch(void* const* d_in, const int* in_sizes, int n_in,
                              void* d_out, int out_size, void* d_ws, size_t ws_size,
                              hipStream_t stream) {
  (void)in_sizes; (void)n_in; (void)out_size; (void)ws_size;
  const float* seq  = (const float*)d_in[0];
  const float* base = (const float*)d_in[1];
  const float* Wp   = (const float*)d_in[2];
  const float* Wpb  = (const float*)d_in[3];
  const float* Ua   = (const float*)d_in[4];
  const float* Uab  = (const float*)d_in[5];
  const float* Wmid = (const float*)d_in[6];
  const float* bmid = (const float*)d_in[7];
  const float* wout = (const float*)d_in[8];
  float* out = (float*)d_out;

  float* ws = (float*)d_ws;
  float* tanh_h = ws;                     // (768,512) x2
  float* h_a    = ws + 786432;            // (768,512)
  float* tprd_s = ws + 1179648;           // (3072,128) *C2
  float* tref_s = ws + 1572864;           // (768,128)  *C2, atomic
  unsigned short* targ_s = (unsigned short*)(ws + 1671168);  // (3072,128) bf16
  unsigned* bar = (unsigned*)((char*)d_ws + (16u << 20));    // barrier cells

  mono<<<dim3(NBLK), dim3(256), 0, stream>>>(
      seq, base, Wp, Wpb, Ua, Uab, Wmid, bmid, wout, out,
      tanh_h, h_a, tprd_s, tref_s, targ_s, bar);
}

// Round 7
// 172.273 us; speedup vs baseline: 2.2889x; 2.2889x over previous
//
#include <hip/hip_runtime.h>
#include <hip/hip_bf16.h>

// RefinementLayer2: B=2,S=384,C=4,H=128,D=768 — single kernel, SW grid barrier.
// ws layout (floats):
//   0        tanh_h   (786432) = tanh(seq@{Wp,Ua}+b), z=0/1 slices (768,512)
//   786432   h_a      (393216) = seq@Ua+b         (768,512)
//   1179648  tprd_s   (393216) = C2*tanh(h_p)@W1  (3072,128)
//   1572864  tref_s   (98304)  = C2*tanh(ref)@W3  (768,128)  [atomic-accum]
//   1671168  targ_s   (196608 floats as bf16)     (3072,128)
// barrier cells at byte offset 16 MiB into d_ws.

#define C2 2.885390081777927f  // 2/ln(2): exp2(C2*x) = e^(2x)
#define NBLK 512
#define MAGIC 0x13579BDFu
#define SPIN_MAX (1L << 22)

typedef __attribute__((ext_vector_type(8))) __bf16 bf16x8;
typedef __attribute__((ext_vector_type(8))) unsigned short ushort8;
typedef __attribute__((ext_vector_type(4))) float float4v;

__device__ __forceinline__ unsigned short f2bf(float f) {
  unsigned int u = __float_as_uint(f);
  u += 0x7fffu + ((u >> 16) & 1u);
  return (unsigned short)(u >> 16);
}

__device__ __forceinline__ float fast_tanh(float x) {
  float e = __builtin_amdgcn_exp2f(C2 * x);
  return 1.0f - 2.0f * __builtin_amdgcn_rcpf(1.0f + e);
}

// ---- barrier primitives ----------------------------------------------------
// Polls are RELAXED RMWs: they execute at the coherence point (see cross-XCD
// updates) and carry NO per-iteration L2 invalidate/writeback — R5/R6 used
// acquire loads per poll, whose L2-invalidate storm slowed the kernel ~10x.
__device__ __forceinline__ unsigned rmw_read(unsigned* p) {
  return __hip_atomic_fetch_add(p, 0u, __ATOMIC_RELAXED,
                                __HIP_MEMORY_SCOPE_AGENT);
}
__device__ __forceinline__ void rmw_write(unsigned* p, unsigned v) {
  (void)__hip_atomic_exchange(p, v, __ATOMIC_RELAXED,
                              __HIP_MEMORY_SCOPE_AGENT);
}
__device__ __forceinline__ void fence_rel() {
  __builtin_amdgcn_fence(__ATOMIC_RELEASE, "agent");  // one L2 writeback
}
__device__ __forceinline__ void fence_acq() {
  __builtin_amdgcn_fence(__ATOMIC_ACQUIRE, "agent");  // one L2 invalidate
}

// Software grid barrier. cnt: 8 spread counters (stride 32 u32 = 128 B).
// Block 0 polls the counters and releases; others spin on rel.
// Bounded spins: on a bug we produce wrong results instead of hanging.
__device__ __forceinline__ void grid_barrier(unsigned* cnt, unsigned* rel,
                                             int bid) {
  __syncthreads();
  if (threadIdx.x == 0) {
    fence_rel();  // make this block's stage writes visible at L3
    __hip_atomic_fetch_add(&cnt[(bid & 7) * 32], 1u, __ATOMIC_RELAXED,
                           __HIP_MEMORY_SCOPE_AGENT);
    if (bid == 0) {
      for (long g = 0; g < SPIN_MAX; ++g) {
        unsigned s = 0;
#pragma unroll
        for (int i = 0; i < 8; ++i) s += rmw_read(&cnt[i * 32]);
        if (s == NBLK) break;
        __builtin_amdgcn_s_sleep(8);
      }
      rmw_write(rel, MAGIC);
    } else {
      for (long g = 0; g < SPIN_MAX; ++g) {
        if (rmw_read(rel) == MAGIC) break;
        __builtin_amdgcn_s_sleep(8);
      }
    }
    fence_acq();  // invalidate stale L1/L2 before reading other blocks' data
  }
  __syncthreads();
}

// 64x64-tile bf16-MFMA core, BK=32, 256 threads (4 waves, 32x32 each).
__device__ __forceinline__ void gemm_core(
    const float* __restrict__ Abase, int lda,
    const float* __restrict__ Bbase, int ldb, int K,
    unsigned short* Alds, unsigned short* Blds,
    int ar, int ac, int bk, int bn,
    int wm0, int wn0, int col16, int quad, float4v acc[2][2])
{
  const float* Ap = Abase + (size_t)ar * lda + ac;
  const float* Bp = Bbase + (size_t)bk * ldb + bn;
  float4 a0 = ((const float4*)Ap)[0], a1 = ((const float4*)Ap)[1];
  float4 b0 = ((const float4*)Bp)[0], b1 = ((const float4*)Bp)[1];

  for (int k0 = 0; k0 < K; k0 += 32) {
    __syncthreads();
    {
      ushort8 o;
      o[0] = f2bf(a0.x); o[1] = f2bf(a0.y); o[2] = f2bf(a0.z); o[3] = f2bf(a0.w);
      o[4] = f2bf(a1.x); o[5] = f2bf(a1.y); o[6] = f2bf(a1.z); o[7] = f2bf(a1.w);
      *(ushort8*)&Alds[ar * 40 + ac] = o;
      float vv[8] = {b0.x, b0.y, b0.z, b0.w, b1.x, b1.y, b1.z, b1.w};
#pragma unroll
      for (int j = 0; j < 8; ++j) Blds[(bn + j) * 40 + bk] = f2bf(vv[j]);
    }
    __syncthreads();
    if (k0 + 32 < K) {
      const float4* An = (const float4*)(Ap + k0 + 32);
      const float4* Bn = (const float4*)(Bp + (size_t)(k0 + 32) * ldb);
      a0 = An[0]; a1 = An[1]; b0 = Bn[0]; b1 = Bn[1];
    }
    bf16x8 afrag[2], bfrag[2];
#pragma unroll
    for (int i = 0; i < 2; ++i)
      afrag[i] = __builtin_bit_cast(bf16x8,
          *(const ushort8*)&Alds[(wm0 + i * 16 + col16) * 40 + quad * 8]);
#pragma unroll
    for (int j = 0; j < 2; ++j)
      bfrag[j] = __builtin_bit_cast(bf16x8,
          *(const ushort8*)&Blds[(wn0 + j * 16 + col16) * 40 + quad * 8]);
#pragma unroll
    for (int i = 0; i < 2; ++i)
#pragma unroll
      for (int j = 0; j < 2; ++j)
        acc[i][j] = __builtin_amdgcn_mfma_f32_16x16x32_bf16(
            afrag[i], bfrag[j], acc[i][j], 0, 0, 0);
  }
}

// Co-residency: LDS 28.7KB -> 5 blocks/CU; launch_bounds(256,2) guarantees
// >=2; grid 512 <= 2*256, so the barrier cannot deadlock.
__global__ __launch_bounds__(256, 2) void mono(
    const float* __restrict__ seq, const float* __restrict__ base,
    const float* __restrict__ Wp, const float* __restrict__ Wpb,
    const float* __restrict__ Ua, const float* __restrict__ Uab,
    const float* __restrict__ Wmid, const float* __restrict__ bmid,
    const float* __restrict__ wout, float* __restrict__ out,
    float* __restrict__ tanh_h, float* __restrict__ h_a,
    float* __restrict__ tprd_s, float* __restrict__ tref_s,
    unsigned short* __restrict__ targ_s, unsigned* __restrict__ bar)
{
  __shared__ __align__(16) unsigned char smem[28672];
  unsigned short* Alds = (unsigned short*)smem;            // 5120 B
  unsigned short* Blds = (unsigned short*)(smem + 5120);   // 5120 B

  const int tid = threadIdx.x;
  const int bid = blockIdx.x;
  const int wid = tid >> 6, lane = tid & 63;
  const int wm0 = (wid >> 1) * 32, wn0 = (wid & 1) * 32;
  const int col16 = lane & 15, quad = lane >> 4;
  const int ar = tid >> 2, ac = (tid & 3) * 8;
  const int bk = tid >> 3, bn = (tid & 7) * 8;

  // ---- barrier init (block 0), all via RMW so values land at L3 ----
  if (bid == 0 && tid == 0) {
#pragma unroll
    for (int i = 0; i < 8; ++i) {
      rmw_write(&bar[32 + i * 32], 0u);
      rmw_write(&bar[512 + i * 32], 0u);
    }
    rmw_write(&bar[16], 0u);
    rmw_write(&bar[24], 0u);
    fence_rel();  // order the zeroing RMWs before the MAGIC handshake
    rmw_write(&bar[0], MAGIC);
  }

  // ---------------- Stage 1 ----------------
  if (bid < 192) {
    const int z = bid / 96, rem = bid % 96;
    const int bn0 = (rem & 7) * 64, bm0 = (rem >> 3) * 64;
    const float* Bm = (z ? Ua : Wp) + bn0;
    const float* bias = z ? Uab : Wpb;
    float4v acc[2][2];
#pragma unroll
    for (int i = 0; i < 2; ++i)
#pragma unroll
      for (int j = 0; j < 2; ++j) acc[i][j] = (float4v)(0.f);
    gemm_core(seq + (size_t)bm0 * 768, 768, Bm, 512, 768,
              Alds, Blds, ar, ac, bk, bn, wm0, wn0, col16, quad, acc);
    float* tout = tanh_h + (size_t)z * 393216;
#pragma unroll
    for (int j = 0; j < 2; ++j) {
      const int gcol = bn0 + wn0 + j * 16 + col16;
      const float bv = bias[gcol];
#pragma unroll
      for (int i = 0; i < 2; ++i)
#pragma unroll
        for (int r = 0; r < 4; ++r) {
          const int grow = bm0 + wm0 + i * 16 + quad * 4 + r;
          const float x = acc[i][j][r] + bv;
          const size_t cidx = (size_t)grow * 512 + gcol;
          tout[cidx] = fast_tanh(x);
          if (z == 1) h_a[cidx] = x;
        }
    }
  } else {
    for (int idx = (bid - 192) * 256 + tid; idx < 98304; idx += 81920)
      tref_s[idx] = 0.f;
  }

  // ready handshake (bar cells initialized) then barrier 1
  if (tid == 0) {
    for (long g = 0; g < SPIN_MAX; ++g) {
      if (rmw_read(&bar[0]) == MAGIC) break;
      __builtin_amdgcn_s_sleep(8);
    }
  }
  grid_barrier(&bar[32], &bar[16], bid);

  // ---------------- Stage 2 ----------------
  if (bid < 288) {
    float4v acc[2][2];
#pragma unroll
    for (int i = 0; i < 2; ++i)
#pragma unroll
      for (int j = 0; j < 2; ++j) acc[i][j] = (float4v)(0.f);

    if (bid < 96) {  // heavy: ref tile + tanh + tail MFMA -> atomic tref
      unsigned short* TA = (unsigned short*)smem;           // 64x72, 9216 B
      unsigned short* TB = (unsigned short*)(smem + 9216);  // 128x72, 18432 B
      const int z = bid / 12, rem = bid % 12;
      const int b = z >> 2, c = z & 3;
      const int y = rem >> 1, x = rem & 1;
      const float* A = base + (size_t)b * 589824 + c * 384 + (size_t)(y * 64) * 1536;
      const float* Bm = h_a + (size_t)b * 196608 + c * 128 + x * 64;
      gemm_core(A, 1536, Bm, 512, 384, Alds, Blds, ar, ac, bk, bn,
                wm0, wn0, col16, quad, acc);
      __syncthreads();  // TA overlaps Alds/Blds — drain gemm_core LDS reads
#pragma unroll
      for (int j = 0; j < 2; ++j)
#pragma unroll
        for (int i = 0; i < 2; ++i)
#pragma unroll
          for (int r = 0; r < 4; ++r)
            TA[(wm0 + i * 16 + quad * 4 + r) * 72 + wn0 + j * 16 + col16] =
                f2bf(fast_tanh(acc[i][j][r]));
      {
        const float* W3p = Wmid + 32768 + (size_t)(c * 128 + x * 64) * 128;
        const int kr = tid >> 2, nb = (tid & 3) * 32;
#pragma unroll
        for (int q = 0; q < 8; ++q) {
          float4 v = *(const float4*)(W3p + (size_t)kr * 128 + nb + q * 4);
          TB[(nb + q * 4 + 0) * 72 + kr] = f2bf(v.x);
          TB[(nb + q * 4 + 1) * 72 + kr] = f2bf(v.y);
          TB[(nb + q * 4 + 2) * 72 + kr] = f2bf(v.z);
          TB[(nb + q * 4 + 3) * 72 + kr] = f2bf(v.w);
        }
      }
      __syncthreads();
      const int mh = wid & 1, nh = wid >> 1;
      float4v acc2[2][4];
#pragma unroll
      for (int i = 0; i < 2; ++i)
#pragma unroll
        for (int j = 0; j < 4; ++j) acc2[i][j] = (float4v)(0.f);
#pragma unroll
      for (int ks = 0; ks < 2; ++ks) {
        bf16x8 af[2], bf[4];
#pragma unroll
        for (int i = 0; i < 2; ++i)
          af[i] = __builtin_bit_cast(bf16x8,
              *(const ushort8*)&TA[(mh * 32 + i * 16 + col16) * 72 + ks * 32 + quad * 8]);
#pragma unroll
        for (int j = 0; j < 4; ++j)
          bf[j] = __builtin_bit_cast(bf16x8,
              *(const ushort8*)&TB[(nh * 64 + j * 16 + col16) * 72 + ks * 32 + quad * 8]);
#pragma unroll
        for (int i = 0; i < 2; ++i)
#pragma unroll
          for (int j = 0; j < 4; ++j)
            acc2[i][j] = __builtin_amdgcn_mfma_f32_16x16x32_bf16(
                af[i], bf[j], acc2[i][j], 0, 0, 0);
      }
#pragma unroll
      for (int j = 0; j < 4; ++j) {
        const int gcol = nh * 64 + j * 16 + col16;
#pragma unroll
        for (int i = 0; i < 2; ++i)
#pragma unroll
          for (int r = 0; r < 4; ++r) {
            const int grow = b * 384 + y * 64 + mh * 32 + i * 16 + quad * 4 + r;
            atomicAdd(&tref_s[(size_t)grow * 128 + gcol], C2 * acc2[i][j][r]);
          }
      }
    } else {  // light: tanh_h{p,a}@W{1,2}
      const int idx = bid - 96;
      const int x = idx & 1, y = (idx >> 1) % 48, z = idx / 96;
      const float* A = tanh_h + (size_t)z * 393216 + (size_t)(y * 64) * 128;
      const float* Bm = Wmid + z * 16384 + x * 64;
      gemm_core(A, 128, Bm, 128, 128, Alds, Blds, ar, ac, bk, bn,
                wm0, wn0, col16, quad, acc);
#pragma unroll
      for (int j = 0; j < 2; ++j) {
        const int gcol = x * 64 + wn0 + j * 16 + col16;
#pragma unroll
        for (int i = 0; i < 2; ++i)
#pragma unroll
          for (int r = 0; r < 4; ++r) {
            const int grow = y * 64 + wm0 + i * 16 + quad * 4 + r;
            const float v = C2 * acc[i][j][r];
            const size_t cidx = (size_t)grow * 128 + gcol;
            if (z == 0) tprd_s[cidx] = v;
            else        targ_s[cidx] = f2bf(v);
          }
      }
    }
  }

  grid_barrier(&bar[512], &bar[24], bid);

  // ---------------- Stage 3 (phase2) ----------------
  // threads: a = tid&127, kh = tid>>7. k split: h in {0,1} passes of 64 k,
  // each pass kh-split into 32-k quarters. 4-way rcp pairing.
  unsigned int* Gs = (unsigned int*)smem;        // [128][34], 17408 B
  float* Es  = (float*)(smem + 17408);           // [8][128],  4096 B
  float* Ws  = (float*)(smem + 21504);           // [128],      512 B
  float* Red = (float*)(smem + 22016);           // [128][9],  4608 B

  if (tid < 128) Ws[tid] = -2.f * wout[tid];
  float sw = 0.f;
  for (int k4 = 0; k4 < 32; ++k4) {
    float4 w = ((const float4*)wout)[k4];
    sw += w.x + w.y + w.z + w.w;
  }

  const unsigned int* gsrc = (const unsigned int*)targ_s;
  const int a = tid & 127, kh = tid >> 7;
  const int j0 = (bid * 9) >> 2, j1 = ((bid + 1) * 9) >> 2;  // 1152 jobs

  for (int job = j0; job < j1; ++job) {
    const int s = job / 48, pt = job % 48;
    const int at = s % 3, zz = s / 3;
    const int b = zz >> 2, c = zz & 3;
    const int p0 = pt * 8, a0 = at * 128;
    const size_t gb = (size_t)((b * 384 + a0) * 4 + c) * 64;

    __syncthreads();  // prior job's readers done; Ws visible on first
#pragma unroll
    for (int it = 0; it < 4; ++it) {  // Es[8][128]
      int idx = it * 256 + tid;
      int p = idx >> 7, k = idx & 127;
      int row = b * 384 + p0 + p;
      Es[idx] = __builtin_amdgcn_exp2f(
          tprd_s[(size_t)(row * 4 + c) * 128 + k] +
          tref_s[(size_t)row * 128 + k] + C2 * bmid[k]);
    }

    float acc[8];
#pragma unroll
    for (int p = 0; p < 8; ++p) acc[p] = 0.f;

    for (int h = 0; h < 2; ++h) {
      if (h) __syncthreads();  // h=0 compute done reading Gs
#pragma unroll 4
      for (int it = 0; it < 16; ++it) {  // Gs: 128 rows x 32 uints
        int idx = it * 256 + tid;
        int r = idx >> 5, col = idx & 31;
        Gs[r * 34 + col] = gsrc[gb + (size_t)r * 256 + h * 32 + col];
      }
      __syncthreads();

      const unsigned int* g = &Gs[a * 34 + kh * 16];
      const int kb = h * 64 + kh * 32;
#pragma unroll 2
      for (int j = 0; j < 8; ++j) {  // 4 k per j
        uint2 gp = *(const uint2*)(g + j * 2);
        float eg0 = __builtin_amdgcn_exp2f(__uint_as_float(gp.x << 16));
        float eg1 = __builtin_amdgcn_exp2f(__uint_as_float(gp.x & 0xffff0000u));
        float eg2 = __builtin_amdgcn_exp2f(__uint_as_float(gp.y << 16));
        float eg3 = __builtin_amdgcn_exp2f(__uint_as_float(gp.y & 0xffff0000u));
        float4 wq = *(const float4*)&Ws[kb + j * 4];
#pragma unroll
        for (int p = 0; p < 8; ++p) {
          float4 ef = *(const float4*)&Es[p * 128 + kb + j * 4];
          float d0 = fmaf(ef.x, eg0, 1.f);
          float d1 = fmaf(ef.y, eg1, 1.f);
          float d2 = fmaf(ef.z, eg2, 1.f);
          float d3 = fmaf(ef.w, eg3, 1.f);
          float d01 = d0 * d1, d23 = d2 * d3;
          float n01 = fmaf(wq.y, d0, wq.x * d1);
          float n23 = fmaf(wq.w, d2, wq.z * d3);
          float num = fmaf(n01, d23, n23 * d01);
          float r = __builtin_amdgcn_rcpf(d01 * d23);
          acc[p] = fmaf(num, r, acc[p]);
        }
      }
    }

    if (kh) {
#pragma unroll
      for (int p = 0; p < 8; ++p) Red[a * 9 + p] = acc[p];
    }
    __syncthreads();
    if (!kh) {
      const size_t ob = (size_t)((b * 384 + p0) * 4 + c) * 384 + a0 + a;
#pragma unroll
      for (int p = 0; p < 8; ++p)
        out[ob + (size_t)p * 1536] = sw + acc[p] + Red[a * 9 + p];
    }
  }
}

extern "C" void kernel_launch(void* const* d_in, const int* in_sizes, int n_in,
                              void* d_out, int out_size, void* d_ws, size_t ws_size,
                              hipStream_t stream) {
  (void)in_sizes; (void)n_in; (void)out_size; (void)ws_size;
  const float* seq  = (const float*)d_in[0];
  const float* base = (const float*)d_in[1];
  const float* Wp   = (const float*)d_in[2];
  const float* Wpb  = (const float*)d_in[3];
  const float* Ua   = (const float*)d_in[4];
  const float* Uab  = (const float*)d_in[5];
  const float* Wmid = (const float*)d_in[6];
  const float* bmid = (const float*)d_in[7];
  const float* wout = (const float*)d_in[8];
  float* out = (float*)d_out;

  float* ws = (float*)d_ws;
  float* tanh_h = ws;                     // (768,512) x2
  float* h_a    = ws + 786432;            // (768,512)
  float* tprd_s = ws + 1179648;           // (3072,128) *C2
  float* tref_s = ws + 1572864;           // (768,128)  *C2, atomic
  unsigned short* targ_s = (unsigned short*)(ws + 1671168);  // (3072,128) bf16
  unsigned* bar = (unsigned*)((char*)d_ws + (16u << 20));    // barrier cells

  mono<<<dim3(NBLK), dim3(256), 0, stream>>>(
      seq, base, Wp, Wpb, Ua, Uab, Wmid, bmid, wout, out,
      tanh_h, h_a, tprd_s, tref_s, targ_s, bar);
}

// Round 8
// 131.640 us; speedup vs baseline: 2.9954x; 1.3087x over previous
//
#include <hip/hip_runtime.h>
#include <hip/hip_bf16.h>

// RefinementLayer2: B=2,S=384,C=4,H=128,D=768 — 3 dispatches (R3 structure).
// ws layout (floats):
//   0        tanh_h   (786432) = tanh(seq@{Wp,Ua}+b), z=0/1 slices (768,512)
//   786432   h_a      (393216) = seq@Ua+b         (768,512)
//   1179648  tprd_s   (393216) = C2*tanh(h_p)@W1  (3072,128)
//   1572864  tref_s   (98304)  = C2*tanh(ref)@W3  (768,128)  [atomic-accum]
//   1671168  targ_s   (196608 floats as bf16)     (3072,128)

#define C2 2.885390081777927f  // 2/ln(2): exp2(C2*x) = e^(2x)

typedef __attribute__((ext_vector_type(8))) __bf16 bf16x8;
typedef __attribute__((ext_vector_type(8))) unsigned short ushort8;
typedef __attribute__((ext_vector_type(4))) float float4v;

__device__ __forceinline__ unsigned short f2bf(float f) {
  unsigned int u = __float_as_uint(f);
  u += 0x7fffu + ((u >> 16) & 1u);
  return (unsigned short)(u >> 16);
}

__device__ __forceinline__ float fast_tanh(float x) {
  float e = __builtin_amdgcn_exp2f(C2 * x);
  return 1.0f - 2.0f * __builtin_amdgcn_rcpf(1.0f + e);
}

// 64x64-tile bf16-MFMA core, BK=32, 256 threads (4 waves, 32x32 each).
__device__ __forceinline__ void gemm_core(
    const float* __restrict__ Abase, int lda,
    const float* __restrict__ Bbase, int ldb, int K,
    unsigned short* Alds, unsigned short* Blds,
    int ar, int ac, int bk, int bn,
    int wm0, int wn0, int col16, int quad, float4v acc[2][2])
{
  const float* Ap = Abase + (size_t)ar * lda + ac;
  const float* Bp = Bbase + (size_t)bk * ldb + bn;
  float4 a0 = ((const float4*)Ap)[0], a1 = ((const float4*)Ap)[1];
  float4 b0 = ((const float4*)Bp)[0], b1 = ((const float4*)Bp)[1];

  for (int k0 = 0; k0 < K; k0 += 32) {
    __syncthreads();
    {
      ushort8 o;
      o[0] = f2bf(a0.x); o[1] = f2bf(a0.y); o[2] = f2bf(a0.z); o[3] = f2bf(a0.w);
      o[4] = f2bf(a1.x); o[5] = f2bf(a1.y); o[6] = f2bf(a1.z); o[7] = f2bf(a1.w);
      *(ushort8*)&Alds[ar * 40 + ac] = o;
      float vv[8] = {b0.x, b0.y, b0.z, b0.w, b1.x, b1.y, b1.z, b1.w};
#pragma unroll
      for (int j = 0; j < 8; ++j) Blds[(bn + j) * 40 + bk] = f2bf(vv[j]);
    }
    __syncthreads();
    if (k0 + 32 < K) {
      const float4* An = (const float4*)(Ap + k0 + 32);
      const float4* Bn = (const float4*)(Bp + (size_t)(k0 + 32) * ldb);
      a0 = An[0]; a1 = An[1]; b0 = Bn[0]; b1 = Bn[1];
    }
    bf16x8 afrag[2], bfrag[2];
#pragma unroll
    for (int i = 0; i < 2; ++i)
      afrag[i] = __builtin_bit_cast(bf16x8,
          *(const ushort8*)&Alds[(wm0 + i * 16 + col16) * 40 + quad * 8]);
#pragma unroll
    for (int j = 0; j < 2; ++j)
      bfrag[j] = __builtin_bit_cast(bf16x8,
          *(const ushort8*)&Blds[(wn0 + j * 16 + col16) * 40 + quad * 8]);
#pragma unroll
    for (int i = 0; i < 2; ++i)
#pragma unroll
      for (int j = 0; j < 2; ++j)
        acc[i][j] = __builtin_amdgcn_mfma_f32_16x16x32_bf16(
            afrag[i], bfrag[j], acc[i][j], 0, 0, 0);
  }
}

// D1: z=0: tanh(seq@Wp+b); z=1: seq@Ua+b -> h_a (+tanh); z=2: zero tref.
__global__ __launch_bounds__(256) void g1_dual(
    const float* __restrict__ seq, const float* __restrict__ Wp,
    const float* __restrict__ Ua, const float* __restrict__ Wpb,
    const float* __restrict__ Uab, float* __restrict__ tanh_out,
    float* __restrict__ h_a, float* __restrict__ tref_clear)
{
  const int z = blockIdx.z;
  if (z == 2) {
    int idx = ((blockIdx.y * 8 + blockIdx.x) * 256 + threadIdx.x) * 4;
    *(float4*)&tref_clear[idx] = float4{0.f, 0.f, 0.f, 0.f};
    return;
  }
  __shared__ unsigned short Alds[64 * 40];
  __shared__ unsigned short Blds[64 * 40];
  const int tid = threadIdx.x;
  const int bn0 = blockIdx.x * 64, bm0 = blockIdx.y * 64;
  const int wid = tid >> 6, lane = tid & 63;
  const int wm0 = (wid >> 1) * 32, wn0 = (wid & 1) * 32;
  const int col16 = lane & 15, quad = lane >> 4;
  const float* B = z ? Ua : Wp;
  const float* bias = z ? Uab : Wpb;

  float4v acc[2][2];
#pragma unroll
  for (int i = 0; i < 2; ++i)
#pragma unroll
    for (int j = 0; j < 2; ++j) acc[i][j] = (float4v)(0.f);

  gemm_core(seq + (size_t)bm0 * 768, 768, B + bn0, 512, 768,
            Alds, Blds, tid >> 2, (tid & 3) * 8, tid >> 3, (tid & 7) * 8,
            wm0, wn0, col16, quad, acc);

  float* tout = tanh_out + (size_t)z * 393216;
#pragma unroll
  for (int j = 0; j < 2; ++j) {
    const int gcol = bn0 + wn0 + j * 16 + col16;
    const float bv = bias[gcol];
#pragma unroll
    for (int i = 0; i < 2; ++i)
#pragma unroll
      for (int r = 0; r < 4; ++r) {
        const int grow = bm0 + wm0 + i * 16 + quad * 4 + r;
        const float x = acc[i][j][r] + bv;
        const size_t cidx = (size_t)grow * 512 + gcol;
        tout[cidx] = fast_tanh(x);
        if (z == 1) h_a[cidx] = x;
      }
  }
}

// D2: job table, 288 blocks.
//  bid<96 : ref tile = base[b,:,c,:]@h_a[b,:,c,:] (64x64,K=384) -> tanh ->
//           tail MFMA: tref[rows,0:128] += C2*tanh(tile)@W3slice (atomicAdd).
//  bid>=96: tanh_h{p,a}@W{1,2} -> tprd fp32 / targ bf16, *C2.
__global__ __launch_bounds__(256) void fused_mid(
    const float* __restrict__ base, const float* __restrict__ h_a,
    const float* __restrict__ tanh_h, const float* __restrict__ Wmid,
    float* __restrict__ tprd_s, unsigned short* __restrict__ targ_s,
    float* __restrict__ tref_s)
{
  __shared__ unsigned short Alds[64 * 40];
  __shared__ unsigned short Blds[64 * 40];
  __shared__ unsigned short TA[64 * 72];
  __shared__ unsigned short TB[128 * 72];

  const int tid = threadIdx.x;
  const int bid = blockIdx.x;
  const int wid = tid >> 6, lane = tid & 63;
  const int wm0 = (wid >> 1) * 32, wn0 = (wid & 1) * 32;
  const int col16 = lane & 15, quad = lane >> 4;
  const int ar = tid >> 2, ac = (tid & 3) * 8;
  const int bk = tid >> 3, bn = (tid & 7) * 8;

  float4v acc[2][2];
#pragma unroll
  for (int i = 0; i < 2; ++i)
#pragma unroll
    for (int j = 0; j < 2; ++j) acc[i][j] = (float4v)(0.f);

  if (bid < 96) {
    const int z = bid / 12, rem = bid % 12;
    const int b = z >> 2, c = z & 3;
    const int y = rem >> 1, x = rem & 1;
    const float* A = base + (size_t)b * 589824 + c * 384 + (size_t)(y * 64) * 1536;
    const float* Bm = h_a + (size_t)b * 196608 + c * 128 + x * 64;
    gemm_core(A, 1536, Bm, 512, 384, Alds, Blds, ar, ac, bk, bn,
              wm0, wn0, col16, quad, acc);

#pragma unroll
    for (int j = 0; j < 2; ++j)
#pragma unroll
      for (int i = 0; i < 2; ++i)
#pragma unroll
        for (int r = 0; r < 4; ++r)
          TA[(wm0 + i * 16 + quad * 4 + r) * 72 + wn0 + j * 16 + col16] =
              f2bf(fast_tanh(acc[i][j][r]));
    {
      const float* W3p = Wmid + 32768 + (size_t)(c * 128 + x * 64) * 128;
      const int kr = tid >> 2, nb = (tid & 3) * 32;
#pragma unroll
      for (int q = 0; q < 8; ++q) {
        float4 v = *(const float4*)(W3p + (size_t)kr * 128 + nb + q * 4);
        TB[(nb + q * 4 + 0) * 72 + kr] = f2bf(v.x);
        TB[(nb + q * 4 + 1) * 72 + kr] = f2bf(v.y);
        TB[(nb + q * 4 + 2) * 72 + kr] = f2bf(v.z);
        TB[(nb + q * 4 + 3) * 72 + kr] = f2bf(v.w);
      }
    }
    __syncthreads();

    const int mh = wid & 1, nh = wid >> 1;
    float4v acc2[2][4];
#pragma unroll
    for (int i = 0; i < 2; ++i)
#pragma unroll
      for (int j = 0; j < 4; ++j) acc2[i][j] = (float4v)(0.f);
#pragma unroll
    for (int ks = 0; ks < 2; ++ks) {
      bf16x8 af[2], bf[4];
#pragma unroll
      for (int i = 0; i < 2; ++i)
        af[i] = __builtin_bit_cast(bf16x8,
            *(const ushort8*)&TA[(mh * 32 + i * 16 + col16) * 72 + ks * 32 + quad * 8]);
#pragma unroll
      for (int j = 0; j < 4; ++j)
        bf[j] = __builtin_bit_cast(bf16x8,
            *(const ushort8*)&TB[(nh * 64 + j * 16 + col16) * 72 + ks * 32 + quad * 8]);
#pragma unroll
      for (int i = 0; i < 2; ++i)
#pragma unroll
        for (int j = 0; j < 4; ++j)
          acc2[i][j] = __builtin_amdgcn_mfma_f32_16x16x32_bf16(
              af[i], bf[j], acc2[i][j], 0, 0, 0);
    }
#pragma unroll
    for (int j = 0; j < 4; ++j) {
      const int gcol = nh * 64 + j * 16 + col16;
#pragma unroll
      for (int i = 0; i < 2; ++i)
#pragma unroll
        for (int r = 0; r < 4; ++r) {
          const int grow = b * 384 + y * 64 + mh * 32 + i * 16 + quad * 4 + r;
          atomicAdd(&tref_s[(size_t)grow * 128 + gcol], C2 * acc2[i][j][r]);
        }
    }
  } else {
    const int idx = bid - 96;
    const int x = idx & 1, y = (idx >> 1) % 48, z = idx / 96;
    const float* A = tanh_h + (size_t)z * 393216 + (size_t)(y * 64) * 128;
    const float* Bm = Wmid + z * 16384 + x * 64;
    gemm_core(A, 128, Bm, 128, 128, Alds, Blds, ar, ac, bk, bn,
              wm0, wn0, col16, quad, acc);
#pragma unroll
    for (int j = 0; j < 2; ++j) {
      const int gcol = x * 64 + wn0 + j * 16 + col16;
#pragma unroll
      for (int i = 0; i < 2; ++i)
#pragma unroll
        for (int r = 0; r < 4; ++r) {
          const int grow = y * 64 + wm0 + i * 16 + quad * 4 + r;
          const float v = C2 * acc[i][j][r];
          const size_t cidx = (size_t)grow * 128 + gcol;
          if (z == 0) tprd_s[cidx] = v;
          else        targ_s[cidx] = f2bf(v);
        }
    }
  }
}

// D3: out[b,p,c,a] = sum_k w_k * tanh(tprd+targ+tref+bmid).
// 256 threads: a = tid&127, kh = tid>>7 (k half). Each thread holds its own
// t_arg row half IN REGISTERS (8 x uint4 = 64 k bf16) — no Gs LDS tile, no
// bank conflicts, no per-job re-staging. Es (exp2 of per-(p,k) terms) in LDS,
// broadcast reads. Cross-kh reduce via small LDS Red (validated R5-R7).
__global__ __launch_bounds__(256) void phase2(
    const float* __restrict__ tprd, const unsigned short* __restrict__ targ,
    const float* __restrict__ tref, const float* __restrict__ bmid,
    const float* __restrict__ wout, float* __restrict__ out)
{
  __shared__ float Es[8 * 128];   // exp2(f[p][k])
  __shared__ float Ws[128];       // -2*w[k]
  __shared__ float Red[128 * 9];  // kh=1 partial sums

  const int tid = threadIdx.x;
  const int a = tid & 127, kh = tid >> 7;
  const int p0 = blockIdx.x * 8, a0 = blockIdx.y * 128;
  const int b = blockIdx.z >> 2, c = blockIdx.z & 3;

  // this thread's t_arg row half -> registers (64 k = 8 uint4)
  const uint4* grow = (const uint4*)((const unsigned int*)targ +
      (size_t)((b * 384 + a0 + a) * 4 + c) * 64 + kh * 32);
  uint4 G[8];
#pragma unroll
  for (int i = 0; i < 8; ++i) G[i] = grow[i];

  if (tid < 128) Ws[tid] = -2.f * wout[tid];
#pragma unroll
  for (int it = 0; it < 4; ++it) {  // Es[8][128]
    int idx = it * 256 + tid;
    int p = idx >> 7, k = idx & 127;
    int row = b * 384 + p0 + p;
    Es[idx] = __builtin_amdgcn_exp2f(
        tprd[(size_t)(row * 4 + c) * 128 + k] +
        tref[(size_t)row * 128 + k] + C2 * bmid[k]);
  }
  float sw = 0.f;  // Sum(w) via uniform loads
  for (int k4 = 0; k4 < 32; ++k4) {
    float4 w = ((const float4*)wout)[k4];
    sw += w.x + w.y + w.z + w.w;
  }
  __syncthreads();

  float acc[8];
#pragma unroll
  for (int p = 0; p < 8; ++p) acc[p] = 0.f;

  const int kb0 = kh * 64;
#pragma unroll
  for (int j = 0; j < 8; ++j) {  // 8 k per j, from registers G[j]
    const uint4 gq = G[j];
    const float eg0 = __builtin_amdgcn_exp2f(__uint_as_float(gq.x << 16));
    const float eg1 = __builtin_amdgcn_exp2f(__uint_as_float(gq.x & 0xffff0000u));
    const float eg2 = __builtin_amdgcn_exp2f(__uint_as_float(gq.y << 16));
    const float eg3 = __builtin_amdgcn_exp2f(__uint_as_float(gq.y & 0xffff0000u));
    const float eg4 = __builtin_amdgcn_exp2f(__uint_as_float(gq.z << 16));
    const float eg5 = __builtin_amdgcn_exp2f(__uint_as_float(gq.z & 0xffff0000u));
    const float eg6 = __builtin_amdgcn_exp2f(__uint_as_float(gq.w << 16));
    const float eg7 = __builtin_amdgcn_exp2f(__uint_as_float(gq.w & 0xffff0000u));
    const int kb = kb0 + j * 8;
    const float4 wqA = *(const float4*)&Ws[kb];
    const float4 wqB = *(const float4*)&Ws[kb + 4];
#pragma unroll
    for (int p = 0; p < 8; ++p) {
      const float4 efA = *(const float4*)&Es[p * 128 + kb];
      const float4 efB = *(const float4*)&Es[p * 128 + kb + 4];
      float d0 = fmaf(efA.x, eg0, 1.f);
      float d1 = fmaf(efA.y, eg1, 1.f);
      float d2 = fmaf(efA.z, eg2, 1.f);
      float d3 = fmaf(efA.w, eg3, 1.f);
      float d01 = d0 * d1, d23 = d2 * d3;
      float n01 = fmaf(wqA.y, d0, wqA.x * d1);
      float n23 = fmaf(wqA.w, d2, wqA.z * d3);
      float num = fmaf(n01, d23, n23 * d01);
      acc[p] = fmaf(num, __builtin_amdgcn_rcpf(d01 * d23), acc[p]);
      d0 = fmaf(efB.x, eg4, 1.f);
      d1 = fmaf(efB.y, eg5, 1.f);
      d2 = fmaf(efB.z, eg6, 1.f);
      d3 = fmaf(efB.w, eg7, 1.f);
      d01 = d0 * d1; d23 = d2 * d3;
      n01 = fmaf(wqB.y, d0, wqB.x * d1);
      n23 = fmaf(wqB.w, d2, wqB.z * d3);
      num = fmaf(n01, d23, n23 * d01);
      acc[p] = fmaf(num, __builtin_amdgcn_rcpf(d01 * d23), acc[p]);
    }
  }

  if (kh) {
#pragma unroll
    for (int p = 0; p < 8; ++p) Red[a * 9 + p] = acc[p];
  }
  __syncthreads();
  if (!kh) {
    const size_t ob = (size_t)((b * 384 + p0) * 4 + c) * 384 + a0 + a;
#pragma unroll
    for (int p = 0; p < 8; ++p)
      out[ob + (size_t)p * 1536] = sw + acc[p] + Red[a * 9 + p];
  }
}

extern "C" void kernel_launch(void* const* d_in, const int* in_sizes, int n_in,
                              void* d_out, int out_size, void* d_ws, size_t ws_size,
                              hipStream_t stream) {
  (void)in_sizes; (void)n_in; (void)out_size; (void)ws_size;
  const float* seq  = (const float*)d_in[0];
  const float* base = (const float*)d_in[1];
  const float* Wp   = (const float*)d_in[2];
  const float* Wpb  = (const float*)d_in[3];
  const float* Ua   = (const float*)d_in[4];
  const float* Uab  = (const float*)d_in[5];
  const float* Wmid = (const float*)d_in[6];
  const float* bmid = (const float*)d_in[7];
  const float* wout = (const float*)d_in[8];
  float* out = (float*)d_out;

  float* ws = (float*)d_ws;
  float* tanh_h = ws;                     // (768,512) x2 (z=0 hp, z=1 ha)
  float* h_a    = ws + 786432;            // (768,512)
  float* tprd_s = ws + 1179648;           // (3072,128) *C2
  float* tref_s = ws + 1572864;           // (768,128)  *C2, atomic
  unsigned short* targ_s = (unsigned short*)(ws + 1671168);  // (3072,128) bf16

  g1_dual<<<dim3(8, 12, 3), dim3(256), 0, stream>>>(
      seq, Wp, Ua, Wpb, Uab, tanh_h, h_a, tref_s);
  fused_mid<<<dim3(288), dim3(256), 0, stream>>>(
      base, h_a, tanh_h, Wmid, tprd_s, targ_s, tref_s);
  phase2<<<dim3(48, 3, 8), dim3(256), 0, stream>>>(
      tprd_s, targ_s, tref_s, bmid, wout, out);
}